// Round 1
// baseline (1939.531 us; speedup 1.0000x reference)
//
#include <hip/hip_runtime.h>
#include <math.h>

constexpr int NTOT = 65536;
constexpr int D    = 128;
constexpr int BG   = 256;
constexpr int E0 = 131072, E1 = 104960, E2 = 83968;
constexpr int EG0 = 512, EG1 = 410;
constexpr int KP0 = 410, KP1 = 328;

// ---------- embeddings ----------
__global__ __launch_bounds__(256) void k_embed_x(const int* __restrict__ xi,
                                                 const float* __restrict__ tab,
                                                 float* __restrict__ x) {
  int t = blockIdx.x * 256 + threadIdx.x;      // NTOT*32 threads
  int v = t >> 5, q = (t & 31) << 2;
  float4 s = {0.f, 0.f, 0.f, 0.f};
#pragma unroll
  for (int j = 0; j < 9; ++j) {
    int r = xi[v * 9 + j];
    float4 a = *(const float4*)&tab[r * D + q];
    s.x += a.x; s.y += a.y; s.z += a.z; s.w += a.w;
  }
  *(float4*)&x[v * D + q] = s;
}

__global__ __launch_bounds__(256) void k_embed_e(const int* __restrict__ bi,
                                                 const float* __restrict__ tab,
                                                 float* __restrict__ e) {
  int t = blockIdx.x * 256 + threadIdx.x;      // E0*32 threads
  int i = t >> 5, q = (t & 31) << 2;
  float4 s = {0.f, 0.f, 0.f, 0.f};
#pragma unroll
  for (int j = 0; j < 3; ++j) {
    int r = bi[i * 3 + j];
    float4 a = *(const float4*)&tab[r * D + q];
    s.x += a.x; s.y += a.y; s.z += a.z; s.w += a.w;
  }
  *(float4*)&e[i * D + q] = s;
}

// ---------- degree / incidence counts ----------
__global__ __launch_bounds__(256) void k_count(const int* __restrict__ ei, int E,
                                               float* __restrict__ bc,
                                               float* __restrict__ degc) {
  int i = blockIdx.x * 256 + threadIdx.x;
  if (i >= E) return;
  int s = ei[i], d = ei[E + i];
  atomicAdd(&bc[s], 1.f);
  atomicAdd(&bc[d], 1.f);
  atomicAdd(&degc[s], 1.f);
}

// ---------- GEMM: C[M][128] = A[M][128] @ W[128][128] (+bias) ----------
__global__ __launch_bounds__(256) void k_gemm128(const float* __restrict__ A,
                                                 const float* __restrict__ W,
                                                 const float* __restrict__ bias,
                                                 float* __restrict__ C) {
  __shared__ float As[64][36];
  __shared__ float Ws[32][132];
  const int t  = threadIdx.x;
  const int m0 = blockIdx.x * 64;
  const int rg = t >> 4, cg = t & 15;
  const int c0 = cg * 4, c1 = 64 + cg * 4;
  float acc[4][8] = {};
  for (int k0 = 0; k0 < 128; k0 += 32) {
    for (int q = t; q < 512; q += 256) {           // A tile 64x32
      int r = q >> 3, cc = (q & 7) << 2;
      *(float4*)&As[r][cc] = *(const float4*)&A[(m0 + r) * 128 + k0 + cc];
    }
    for (int q = t; q < 1024; q += 256) {          // W tile 32x128
      int r = q >> 5, cc = (q & 31) << 2;
      *(float4*)&Ws[r][cc] = *(const float4*)&W[(k0 + r) * 128 + cc];
    }
    __syncthreads();
#pragma unroll 8
    for (int k = 0; k < 32; ++k) {
      float a[4] = {As[rg * 4 + 0][k], As[rg * 4 + 1][k],
                    As[rg * 4 + 2][k], As[rg * 4 + 3][k]};
      float4 w0 = *(float4*)&Ws[k][c0];
      float4 w1 = *(float4*)&Ws[k][c1];
#pragma unroll
      for (int i2 = 0; i2 < 4; ++i2) {
        acc[i2][0] += a[i2] * w0.x; acc[i2][1] += a[i2] * w0.y;
        acc[i2][2] += a[i2] * w0.z; acc[i2][3] += a[i2] * w0.w;
        acc[i2][4] += a[i2] * w1.x; acc[i2][5] += a[i2] * w1.y;
        acc[i2][6] += a[i2] * w1.z; acc[i2][7] += a[i2] * w1.w;
      }
    }
    __syncthreads();
  }
  float4 b0 = {0.f,0.f,0.f,0.f}, b1 = {0.f,0.f,0.f,0.f};
  if (bias) { b0 = *(const float4*)&bias[c0]; b1 = *(const float4*)&bias[c1]; }
#pragma unroll
  for (int i2 = 0; i2 < 4; ++i2) {
    int r = m0 + rg * 4 + i2;
    float4 o0 = {acc[i2][0]+b0.x, acc[i2][1]+b0.y, acc[i2][2]+b0.z, acc[i2][3]+b0.w};
    float4 o1 = {acc[i2][4]+b1.x, acc[i2][5]+b1.y, acc[i2][6]+b1.z, acc[i2][7]+b1.w};
    *(float4*)&C[r * 128 + c0] = o0;
    *(float4*)&C[r * 128 + c1] = o1;
  }
}

// ---------- GCN message scatter ----------
__global__ __launch_bounds__(256) void k_msg(const int* __restrict__ ei, int E,
                                             const float* __restrict__ e,
                                             const float* __restrict__ h,
                                             const float* __restrict__ degc,
                                             const float* __restrict__ ew,
                                             float* __restrict__ acc) {
  int t = blockIdx.x * 256 + threadIdx.x;       // E*32 threads
  int i = t >> 5, q = (t & 31) << 2;
  if (i >= E) return;
  int s = ei[i], d = ei[E + i];
  float coef = rsqrtf((degc[s] + 1.f) * (degc[d] + 1.f));
  if (ew) coef *= ew[i];
  float4 hv = *(const float4*)&h[s * 128 + q];
  float4 ev = *(const float4*)&e[i * 128 + q];
  float m0 = coef * fmaxf(hv.x + ev.x, 0.f);
  float m1 = coef * fmaxf(hv.y + ev.y, 0.f);
  float m2 = coef * fmaxf(hv.z + ev.z, 0.f);
  float m3 = coef * fmaxf(hv.w + ev.w, 0.f);
  atomicAdd(&acc[d * 128 + q + 0], m0);
  atomicAdd(&acc[d * 128 + q + 1], m1);
  atomicAdd(&acc[d * 128 + q + 2], m2);
  atomicAdd(&acc[d * 128 + q + 3], m3);
}

// ---------- x = relu(acc + relu(h+root)/deg) ----------
__global__ __launch_bounds__(256) void k_xfin(const float* __restrict__ acc,
                                              const float* __restrict__ h,
                                              const float* __restrict__ degc,
                                              const float* __restrict__ root,
                                              float* __restrict__ x) {
  int t = blockIdx.x * 256 + threadIdx.x;       // NTOT*32 threads
  int v = t >> 5, q = (t & 31) << 2;
  float inv = 1.f / (degc[v] + 1.f);
  float4 a = *(const float4*)&acc[v * 128 + q];
  float4 hv = *(const float4*)&h[v * 128 + q];
  float4 r = *(const float4*)&root[q];
  float4 o;
  o.x = fmaxf(a.x + fmaxf(hv.x + r.x, 0.f) * inv, 0.f);
  o.y = fmaxf(a.y + fmaxf(hv.y + r.y, 0.f) * inv, 0.f);
  o.z = fmaxf(a.z + fmaxf(hv.z + r.z, 0.f) * inv, 0.f);
  o.w = fmaxf(a.w + fmaxf(hv.w + r.w, 0.f) * inv, 0.f);
  *(float4*)&x[v * 128 + q] = o;
}

// ---------- per-graph readout: xs += [max, mean, sum] ----------
__global__ __launch_bounds__(256) void k_readout(const float* __restrict__ x,
                                                 float* __restrict__ xs) {
  int t = blockIdx.x * 256 + threadIdx.x;       // BG*128 threads
  int g = t >> 7, c = t & 127;
  const float* xp = x + (size_t)(g << 8) * 128 + c;
  float mx = -1e30f, sm = 0.f;
  for (int n = 0; n < 256; ++n) {
    float v = xp[n * 128];
    mx = fmaxf(mx, v); sm += v;
  }
  xs[g * 384 + c]       += mx;
  xs[g * 384 + 128 + c] += sm * (1.f / 256.f);
  xs[g * 384 + 256 + c] += sm;
}

// ---------- hyperconv scatter: S[src]+=z, S[dst]+=z ----------
__global__ __launch_bounds__(256) void k_hscat(const int* __restrict__ ei, int E,
                                               const float* __restrict__ z,
                                               float* __restrict__ S) {
  int t = blockIdx.x * 256 + threadIdx.x;       // E*32 threads
  int i = t >> 5, q = (t & 31) << 2;
  if (i >= E) return;
  int s = ei[i], d = ei[E + i];
  float4 zv = *(const float4*)&z[i * 128 + q];
  atomicAdd(&S[s * 128 + q + 0], zv.x);
  atomicAdd(&S[s * 128 + q + 1], zv.y);
  atomicAdd(&S[s * 128 + q + 2], zv.z);
  atomicAdd(&S[s * 128 + q + 3], zv.w);
  atomicAdd(&S[d * 128 + q + 0], zv.x);
  atomicAdd(&S[d * 128 + q + 1], zv.y);
  atomicAdd(&S[d * 128 + q + 2], zv.z);
  atomicAdd(&S[d * 128 + q + 3], zv.w);
}

// ---------- hyperconv gather: e = relu(Dinv*(S[s]*Binv_s + S[d]*Binv_d + z) + b) ----------
__global__ __launch_bounds__(256) void k_hgather(const int* __restrict__ ei, int E,
                                                 const float* __restrict__ z,
                                                 const float* __restrict__ S,
                                                 const float* __restrict__ bc,
                                                 const float* __restrict__ bias,
                                                 float* __restrict__ eout) {
  int t = blockIdx.x * 256 + threadIdx.x;       // E*32 threads
  int i = t >> 5, q = (t & 31) << 2;
  if (i >= E) return;
  int s = ei[i], d = ei[E + i];
  float bs = bc[s], bd = bc[d];
  float bis = (bs > 0.5f && bs != 1.0f) ? 1.f / bs : 0.f;
  float bid = (bd > 0.5f && bd != 1.0f) ? 1.f / bd : 0.f;
  float dn = 1.f + (bs != 1.0f ? 1.f : 0.f) + (bd != 1.0f ? 1.f : 0.f);
  float dinv = 1.f / dn;
  float4 zv = *(const float4*)&z[i * 128 + q];
  float4 Sv = *(const float4*)&S[s * 128 + q];
  float4 Dv = *(const float4*)&S[d * 128 + q];
  float4 bv = *(const float4*)&bias[q];
  float4 o;
  o.x = fmaxf(dinv * (Sv.x * bis + Dv.x * bid + zv.x) + bv.x, 0.f);
  o.y = fmaxf(dinv * (Sv.y * bis + Dv.y * bid + zv.y) + bv.y, 0.f);
  o.z = fmaxf(dinv * (Sv.z * bis + Dv.z * bid + zv.z) + bv.z, 0.f);
  o.w = fmaxf(dinv * (Sv.w * bis + Dv.w * bid + zv.w) + bv.w, 0.f);
  *(float4*)&eout[i * 128 + q] = o;
}

// ---------- score dot: zs[i] = e[i] . w ----------
__global__ __launch_bounds__(256) void k_sdot(const float* __restrict__ e,
                                              const float* __restrict__ w,
                                              float* __restrict__ zs, int E) {
  int lane = threadIdx.x & 63;
  int wid  = (blockIdx.x * 256 + threadIdx.x) >> 6;
  int nw   = (gridDim.x * 256) >> 6;
  float w0 = w[lane], w1 = w[lane + 64];
  for (int i = wid; i < E; i += nw) {
    float s = e[i * 128 + lane] * w0 + e[i * 128 + 64 + lane] * w1;
#pragma unroll
    for (int off = 32; off > 0; off >>= 1) s += __shfl_down(s, off);
    if (lane == 0) zs[i] = s;
  }
}

__global__ __launch_bounds__(256) void k_sscat(const int* __restrict__ ei, int E,
                                               const float* __restrict__ zs,
                                               float* __restrict__ Ss) {
  int i = blockIdx.x * 256 + threadIdx.x;
  if (i >= E) return;
  float z = zs[i];
  atomicAdd(&Ss[ei[i]], z);
  atomicAdd(&Ss[ei[E + i]], z);
}

__global__ __launch_bounds__(256) void k_sfin(const int* __restrict__ ei, int E,
                                              const float* __restrict__ zs,
                                              const float* __restrict__ Ss,
                                              const float* __restrict__ bc,
                                              const float* __restrict__ bsc,
                                              float* __restrict__ score) {
  int i = blockIdx.x * 256 + threadIdx.x;
  if (i >= E) return;
  int s = ei[i], d = ei[E + i];
  float bs = bc[s], bd = bc[d];
  float bis = (bs > 0.5f && bs != 1.0f) ? 1.f / bs : 0.f;
  float bid = (bd > 0.5f && bd != 1.0f) ? 1.f / bd : 0.f;
  float dn = 1.f + (bs != 1.0f ? 1.f : 0.f) + (bd != 1.0f ? 1.f : 0.f);
  score[i] = tanhf((Ss[s] * bis + Ss[d] * bid + zs[i]) / dn + bsc[0]);
}

// ---------- per-graph top-k sort + compaction ----------
template <int EG, int KEEP, int ENEW>
__global__ __launch_bounds__(256) void k_sortcompact(const float* __restrict__ score,
                                                     const int* __restrict__ ei_old, int E_old,
                                                     const float* __restrict__ e_old,
                                                     int* __restrict__ ei_new,
                                                     float* __restrict__ e_new,
                                                     float* __restrict__ ew) {
  __shared__ float ss[512];
  __shared__ int   si[512];
  int g = blockIdx.x, t = threadIdx.x;
  for (int i = t; i < 512; i += 256) {
    if (i < EG) { ss[i] = score[g * EG + i]; si[i] = i; }
    else        { ss[i] = -INFINITY;         si[i] = 0x7FFFFFFF; }
  }
  __syncthreads();
  for (int k = 2; k <= 512; k <<= 1) {
    for (int j = k >> 1; j > 0; j >>= 1) {
      for (int i = t; i < 512; i += 256) {
        int ixj = i ^ j;
        if (ixj > i) {
          float s1 = ss[i], s2 = ss[ixj];
          int i1 = si[i], i2 = si[ixj];
          bool firstBetter = (s1 > s2) || (s1 == s2 && i1 < i2);
          bool desc = ((i & k) == 0);
          if (desc != firstBetter) {
            ss[i] = s2; si[i] = i2; ss[ixj] = s1; si[ixj] = i1;
          }
        }
      }
      __syncthreads();
    }
  }
  for (int j = t; j < KEEP; j += 256) {
    int oldp = g * EG + si[j];
    int newp = g * KEEP + j;
    ei_new[newp]        = ei_old[oldp];
    ei_new[ENEW + newp] = ei_old[E_old + oldp];
    ew[newp] = fminf(fmaxf(ss[j], 0.f), 1.f);
  }
  __syncthreads();
  for (int q = t; q < KEEP * 32; q += 256) {
    int j = q >> 5, c4 = (q & 31) << 2;
    *(float4*)&e_new[(size_t)(g * KEEP + j) * 128 + c4] =
        *(const float4*)&e_old[(size_t)(g * EG + si[j]) * 128 + c4];
  }
}

// ---------- final MLP ----------
__global__ __launch_bounds__(128) void k_mlp(const float* __restrict__ xs,
                                             const float* __restrict__ Wc1, const float* __restrict__ bc1,
                                             const float* __restrict__ Wc2, const float* __restrict__ bc2,
                                             const float* __restrict__ Wc3, const float* __restrict__ bc3,
                                             float* __restrict__ out) {
  __shared__ float row[384];
  __shared__ float h1[128];
  __shared__ float h2[64];
  int g = blockIdx.x, t = threadIdx.x;
  for (int i = t; i < 384; i += 128) row[i] = xs[g * 384 + i];
  __syncthreads();
  float a = bc1[t];
  for (int k = 0; k < 384; ++k) a += row[k] * Wc1[k * 128 + t];
  h1[t] = fmaxf(a, 0.f);
  __syncthreads();
  if (t < 64) {
    float b = bc2[t];
    for (int k = 0; k < 128; ++k) b += h1[k] * Wc2[k * 64 + t];
    h2[t] = fmaxf(b, 0.f);
  }
  __syncthreads();
  float o = bc3[t];
  for (int k = 0; k < 64; ++k) o += h2[k] * Wc3[k * 128 + t];
  out[g * 128 + t] = o;
}

extern "C" void kernel_launch(void* const* d_in, const int* in_sizes, int n_in,
                              void* d_out, int out_size, void* d_ws, size_t ws_size,
                              hipStream_t stream) {
  (void)in_sizes; (void)n_in; (void)out_size; (void)ws_size;
  const int*   x_idx  = (const int*)d_in[0];
  const int*   b_idx  = (const int*)d_in[1];
  const int*   ei0    = (const int*)d_in[2];
  const float* atom_t = (const float*)d_in[4];
  const float* bond_t = (const float*)d_in[5];
  const float* W_gcn  = (const float*)d_in[6];
  const float* b_gcn  = (const float*)d_in[7];
  const float* root   = (const float*)d_in[8];
  const float* W_hyp  = (const float*)d_in[9];
  const float* b_hyp  = (const float*)d_in[10];
  const float* W_sc   = (const float*)d_in[11];
  const float* b_sc   = (const float*)d_in[12];
  const float* Wc1    = (const float*)d_in[13];
  const float* bc1_   = (const float*)d_in[14];
  const float* Wc2    = (const float*)d_in[15];
  const float* bc2_   = (const float*)d_in[16];
  const float* Wc3    = (const float*)d_in[17];
  const float* bc3_   = (const float*)d_in[18];
  float* out = (float*)d_out;

  // workspace layout (all f32 unless noted)
  float* x    = (float*)d_ws;
  float* h    = x    + (size_t)NTOT * D;
  float* acc  = h    + (size_t)NTOT * D;     // also reused as hyperconv S
  float* eA   = acc  + (size_t)NTOT * D;
  float* eB   = eA   + (size_t)E0 * D;
  float* degc = eB   + (size_t)E0 * D;
  float* bc   = degc + NTOT;
  float* Ss   = bc   + NTOT;
  float* zs   = Ss   + NTOT;
  float* score= zs   + E0;
  float* ew   = score+ E0;
  float* xs   = ew   + E0;
  int*   eiB  = (int*)(xs + BG * 384);
  int*   eiA2 = eiB + 2 * E0;

  hipMemsetAsync(xs, 0, BG * 384 * 4, stream);
  k_embed_x<<<NTOT * 32 / 256, 256, 0, stream>>>(x_idx, atom_t, x);
  k_embed_e<<<E0 * 32 / 256, 256, 0, stream>>>(b_idx, bond_t, eA);

  const int Es[3] = {E0, E1, E2};
  const int* eis[3] = {ei0, eiB, eiA2};
  float* ebuf[3] = {eA, eB, eA};
  float* zbuf[2] = {eB, eA};
  int*   einew[2] = {eiB, eiA2};
  float* enew[2]  = {eB, eA};
  const float* ewl[3] = {nullptr, ew, ew};

  for (int l = 0; l < 3; ++l) {
    int E = Es[l];
    const int* ei = eis[l];
    float* e = ebuf[l];
    hipMemsetAsync(bc, 0, NTOT * 4, stream);
    hipMemsetAsync(degc, 0, NTOT * 4, stream);
    k_count<<<E / 256, 256, 0, stream>>>(ei, E, bc, degc);
    k_gemm128<<<NTOT / 64, 256, 0, stream>>>(x, W_gcn + (size_t)l * D * D, b_gcn + l * D, h);
    hipMemsetAsync(acc, 0, (size_t)NTOT * D * 4, stream);
    k_msg<<<E * 32 / 256, 256, 0, stream>>>(ei, E, e, h, degc, ewl[l], acc);
    k_xfin<<<NTOT * 32 / 256, 256, 0, stream>>>(acc, h, degc, root + l * D, x);
    k_readout<<<BG * D / 256, 256, 0, stream>>>(x, xs);
    if (l < 2) {
      float* z = zbuf[l];
      k_gemm128<<<E / 64, 256, 0, stream>>>(e, W_hyp + (size_t)l * D * D, nullptr, z);
      hipMemsetAsync(acc, 0, (size_t)NTOT * D * 4, stream);
      k_hscat<<<E * 32 / 256, 256, 0, stream>>>(ei, E, z, acc);
      k_hgather<<<E * 32 / 256, 256, 0, stream>>>(ei, E, z, acc, bc, b_hyp + l * D, e);
      k_sdot<<<1024, 256, 0, stream>>>(e, W_sc + l * D, zs, E);
      hipMemsetAsync(Ss, 0, NTOT * 4, stream);
      k_sscat<<<E / 256, 256, 0, stream>>>(ei, E, zs, Ss);
      k_sfin<<<E / 256, 256, 0, stream>>>(ei, E, zs, Ss, bc, b_sc + l, score);
      if (l == 0)
        k_sortcompact<EG0, KP0, E1><<<BG, 256, 0, stream>>>(score, ei, E, e, einew[0], enew[0], ew);
      else
        k_sortcompact<EG1, KP1, E2><<<BG, 256, 0, stream>>>(score, ei, E, e, einew[1], enew[1], ew);
    }
  }
  k_mlp<<<BG, 128, 0, stream>>>(xs, Wc1, bc1_, Wc2, bc2_, Wc3, bc3_, out);
}

// Round 2
// 926.770 us; speedup vs baseline: 2.0928x; 2.0928x over previous
//
#include <hip/hip_runtime.h>
#include <math.h>

constexpr int NTOT = 65536;
constexpr int D    = 128;
constexpr int BG   = 256;
constexpr int E0 = 131072, E1 = 104960, E2 = 83968;
constexpr int EG0 = 512, EG1 = 410;
constexpr int KP0 = 410, KP1 = 328;

// ---------- embeddings ----------
__global__ __launch_bounds__(256) void k_embed_x(const int* __restrict__ xi,
                                                 const float* __restrict__ tab,
                                                 float* __restrict__ x) {
  int t = blockIdx.x * 256 + threadIdx.x;      // NTOT*32 threads
  int v = t >> 5, q = (t & 31) << 2;
  float4 s = {0.f, 0.f, 0.f, 0.f};
#pragma unroll
  for (int j = 0; j < 9; ++j) {
    int r = xi[v * 9 + j];
    float4 a = *(const float4*)&tab[r * D + q];
    s.x += a.x; s.y += a.y; s.z += a.z; s.w += a.w;
  }
  *(float4*)&x[v * D + q] = s;
}

__global__ __launch_bounds__(256) void k_embed_e(const int* __restrict__ bi,
                                                 const float* __restrict__ tab,
                                                 float* __restrict__ e) {
  int t = blockIdx.x * 256 + threadIdx.x;      // E0*32 threads
  int i = t >> 5, q = (t & 31) << 2;
  float4 s = {0.f, 0.f, 0.f, 0.f};
#pragma unroll
  for (int j = 0; j < 3; ++j) {
    int r = bi[i * 3 + j];
    float4 a = *(const float4*)&tab[r * D + q];
    s.x += a.x; s.y += a.y; s.z += a.z; s.w += a.w;
  }
  *(float4*)&e[i * D + q] = s;
}

// ---------- GEMM: C[M][128] = A[M][128] @ W[128][128] (+bias) ----------
__global__ __launch_bounds__(256) void k_gemm128(const float* __restrict__ A,
                                                 const float* __restrict__ W,
                                                 const float* __restrict__ bias,
                                                 float* __restrict__ C) {
  __shared__ float As[64][36];
  __shared__ float Ws[32][132];
  const int t  = threadIdx.x;
  const int m0 = blockIdx.x * 64;
  const int rg = t >> 4, cg = t & 15;
  const int c0 = cg * 4, c1 = 64 + cg * 4;
  float acc[4][8] = {};
  for (int k0 = 0; k0 < 128; k0 += 32) {
    for (int q = t; q < 512; q += 256) {           // A tile 64x32
      int r = q >> 3, cc = (q & 7) << 2;
      *(float4*)&As[r][cc] = *(const float4*)&A[(m0 + r) * 128 + k0 + cc];
    }
    for (int q = t; q < 1024; q += 256) {          // W tile 32x128
      int r = q >> 5, cc = (q & 31) << 2;
      *(float4*)&Ws[r][cc] = *(const float4*)&W[(k0 + r) * 128 + cc];
    }
    __syncthreads();
#pragma unroll 8
    for (int k = 0; k < 32; ++k) {
      float a[4] = {As[rg * 4 + 0][k], As[rg * 4 + 1][k],
                    As[rg * 4 + 2][k], As[rg * 4 + 3][k]};
      float4 w0 = *(float4*)&Ws[k][c0];
      float4 w1 = *(float4*)&Ws[k][c1];
#pragma unroll
      for (int i2 = 0; i2 < 4; ++i2) {
        acc[i2][0] += a[i2] * w0.x; acc[i2][1] += a[i2] * w0.y;
        acc[i2][2] += a[i2] * w0.z; acc[i2][3] += a[i2] * w0.w;
        acc[i2][4] += a[i2] * w1.x; acc[i2][5] += a[i2] * w1.y;
        acc[i2][6] += a[i2] * w1.z; acc[i2][7] += a[i2] * w1.w;
      }
    }
    __syncthreads();
  }
  float4 b0 = {0.f,0.f,0.f,0.f}, b1 = {0.f,0.f,0.f,0.f};
  if (bias) { b0 = *(const float4*)&bias[c0]; b1 = *(const float4*)&bias[c1]; }
#pragma unroll
  for (int i2 = 0; i2 < 4; ++i2) {
    int r = m0 + rg * 4 + i2;
    float4 o0 = {acc[i2][0]+b0.x, acc[i2][1]+b0.y, acc[i2][2]+b0.z, acc[i2][3]+b0.w};
    float4 o1 = {acc[i2][4]+b1.x, acc[i2][5]+b1.y, acc[i2][6]+b1.z, acc[i2][7]+b1.w};
    *(float4*)&C[r * 128 + c0] = o0;
    *(float4*)&C[r * 128 + c1] = o1;
  }
}

// ---------- fused GCN layer: deg count + message scatter (LDS atomics) +
//            finalize + per-graph readout.  1 block per graph. ----------
template <int EG, bool HAS_EW>
__global__ __launch_bounds__(1024) void k_gcn_fused(const int* __restrict__ ei, int E,
                                                    const float* __restrict__ e,
                                                    const float* __restrict__ h,
                                                    const float* __restrict__ ew,
                                                    const float* __restrict__ root,
                                                    float* __restrict__ x,
                                                    float* __restrict__ xs) {
  __shared__ float acc[256 * 128];     // 128 KB
  __shared__ float degs[256];
  __shared__ float red[2048];          // 8 KB readout partials
  const int g = blockIdx.x, t = threadIdx.x;

  float4* a4 = (float4*)acc;
  float4 z4 = {0.f, 0.f, 0.f, 0.f};
  for (int i = t; i < 8192; i += 1024) a4[i] = z4;
  if (t < 256) degs[t] = 0.f;
  __syncthreads();

  for (int j = t; j < EG; j += 1024) {
    int s = ei[g * EG + j] & 255;
    atomicAdd(&degs[s], 1.f);
  }
  __syncthreads();

  const int wid = t >> 6, lane = t & 63;
  for (int j = wid; j < EG; j += 16) {
    int idx = g * EG + j;
    int s = ei[idx] & 255, d = ei[E + idx] & 255;
    float coef = rsqrtf((degs[s] + 1.f) * (degs[d] + 1.f));
    if (HAS_EW) coef *= ew[idx];
    const float* hp = h + ((size_t)(g * 256 + s)) * 128;
    const float* ep = e + (size_t)idx * 128;
    float m0 = coef * fmaxf(hp[lane] + ep[lane], 0.f);
    float m1 = coef * fmaxf(hp[lane + 64] + ep[lane + 64], 0.f);
    atomicAdd(&acc[d * 128 + lane], m0);
    atomicAdd(&acc[d * 128 + 64 + lane], m1);
  }
  __syncthreads();

  // finalize: x = relu(acc + relu(h+root)/deg); keep x in LDS for readout
  for (int i = t; i < 32768; i += 1024) {
    int n = i >> 7, c = i & 127;
    float inv = 1.f / (degs[n] + 1.f);
    float hv = h[((size_t)(g * 256 + n)) * 128 + c];
    float xv = fmaxf(acc[i] + fmaxf(hv + root[c], 0.f) * inv, 0.f);
    x[((size_t)(g * 256 + n)) * 128 + c] = xv;
    acc[i] = xv;
  }
  __syncthreads();

  // readout: 8 partials per column
  {
    int c = t & 127, r8 = t >> 7;
    float mx = -1e30f, sm = 0.f;
    for (int n = r8; n < 256; n += 8) {
      float v = acc[n * 128 + c];
      mx = fmaxf(mx, v); sm += v;
    }
    red[t] = mx; red[1024 + t] = sm;
  }
  __syncthreads();
  if (t < 128) {
    float M = red[t], S2 = red[1024 + t];
#pragma unroll
    for (int k = 1; k < 8; ++k) {
      M = fmaxf(M, red[k * 128 + t]);
      S2 += red[1024 + k * 128 + t];
    }
    xs[g * 384 + t]       += M;
    xs[g * 384 + 128 + t] += S2 * (1.f / 256.f);
    xs[g * 384 + 256 + t] += S2;
  }
}

// ---------- fused hyperconv + score: bc count + z scatter (LDS) + gather +
//            per-edge score dot + scalar hyperconv + tanh.  1 block/graph. ----------
template <int EG>
__global__ __launch_bounds__(1024) void k_hyper_fused(const int* __restrict__ ei, int E,
                                                      const float* __restrict__ z,
                                                      const float* __restrict__ bias,
                                                      const float* __restrict__ wsc,
                                                      const float* __restrict__ bsc,
                                                      float* __restrict__ eout,
                                                      float* __restrict__ score) {
  __shared__ float S[256 * 128];       // 128 KB
  __shared__ float bcs[256];
  __shared__ float zsh[EG0];
  __shared__ float Ssh[256];
  const int g = blockIdx.x, t = threadIdx.x;

  float4* s4 = (float4*)S;
  float4 z4 = {0.f, 0.f, 0.f, 0.f};
  for (int i = t; i < 8192; i += 1024) s4[i] = z4;
  if (t < 256) { bcs[t] = 0.f; Ssh[t] = 0.f; }
  __syncthreads();

  for (int j = t; j < EG; j += 1024) {
    int s = ei[g * EG + j] & 255, d = ei[E + g * EG + j] & 255;
    atomicAdd(&bcs[s], 1.f);
    atomicAdd(&bcs[d], 1.f);
  }
  __syncthreads();

  const int wid = t >> 6, lane = t & 63;
  for (int j = wid; j < EG; j += 16) {
    int idx = g * EG + j;
    int s = ei[idx] & 255, d = ei[E + idx] & 255;
    const float* zp = z + (size_t)idx * 128;
    float z0 = zp[lane], z1 = zp[lane + 64];
    atomicAdd(&S[s * 128 + lane], z0);
    atomicAdd(&S[s * 128 + 64 + lane], z1);
    atomicAdd(&S[d * 128 + lane], z0);
    atomicAdd(&S[d * 128 + 64 + lane], z1);
  }
  __syncthreads();

  const float w0 = wsc[lane], w1 = wsc[lane + 64];
  for (int j = wid; j < EG; j += 16) {
    int idx = g * EG + j;
    int s = ei[idx] & 255, d = ei[E + idx] & 255;
    float bs = bcs[s], bd = bcs[d];
    float bis = (bs > 0.5f && bs != 1.0f) ? 1.f / bs : 0.f;
    float bid = (bd > 0.5f && bd != 1.0f) ? 1.f / bd : 0.f;
    float dinv = 1.f / (1.f + (bs != 1.0f ? 1.f : 0.f) + (bd != 1.0f ? 1.f : 0.f));
    const float* zp = z + (size_t)idx * 128;
    float z0 = zp[lane], z1 = zp[lane + 64];
    float o0 = fmaxf(dinv * (S[s * 128 + lane] * bis + S[d * 128 + lane] * bid + z0) + bias[lane], 0.f);
    float o1 = fmaxf(dinv * (S[s * 128 + 64 + lane] * bis + S[d * 128 + 64 + lane] * bid + z1) + bias[lane + 64], 0.f);
    eout[(size_t)idx * 128 + lane]      = o0;
    eout[(size_t)idx * 128 + 64 + lane] = o1;
    float part = o0 * w0 + o1 * w1;
#pragma unroll
    for (int off = 32; off > 0; off >>= 1) part += __shfl_xor(part, off);
    if (lane == 0) zsh[j] = part;
  }
  __syncthreads();

  for (int j = t; j < EG; j += 1024) {
    int s = ei[g * EG + j] & 255, d = ei[E + g * EG + j] & 255;
    float v = zsh[j];
    atomicAdd(&Ssh[s], v);
    atomicAdd(&Ssh[d], v);
  }
  __syncthreads();

  for (int j = t; j < EG; j += 1024) {
    int s = ei[g * EG + j] & 255, d = ei[E + g * EG + j] & 255;
    float bs = bcs[s], bd = bcs[d];
    float bis = (bs > 0.5f && bs != 1.0f) ? 1.f / bs : 0.f;
    float bid = (bd > 0.5f && bd != 1.0f) ? 1.f / bd : 0.f;
    float dn = 1.f + (bs != 1.0f ? 1.f : 0.f) + (bd != 1.0f ? 1.f : 0.f);
    score[g * EG + j] = tanhf((Ssh[s] * bis + Ssh[d] * bid + zsh[j]) / dn + bsc[0]);
  }
}

// ---------- per-graph top-k sort + compaction ----------
template <int EG, int KEEP, int ENEW>
__global__ __launch_bounds__(256) void k_sortcompact(const float* __restrict__ score,
                                                     const int* __restrict__ ei_old, int E_old,
                                                     const float* __restrict__ e_old,
                                                     int* __restrict__ ei_new,
                                                     float* __restrict__ e_new,
                                                     float* __restrict__ ew) {
  __shared__ float ss[512];
  __shared__ int   si[512];
  int g = blockIdx.x, t = threadIdx.x;
  for (int i = t; i < 512; i += 256) {
    if (i < EG) { ss[i] = score[g * EG + i]; si[i] = i; }
    else        { ss[i] = -INFINITY;         si[i] = 0x7FFFFFFF; }
  }
  __syncthreads();
  for (int k = 2; k <= 512; k <<= 1) {
    for (int j = k >> 1; j > 0; j >>= 1) {
      for (int i = t; i < 512; i += 256) {
        int ixj = i ^ j;
        if (ixj > i) {
          float s1 = ss[i], s2 = ss[ixj];
          int i1 = si[i], i2 = si[ixj];
          bool firstBetter = (s1 > s2) || (s1 == s2 && i1 < i2);
          bool desc = ((i & k) == 0);
          if (desc != firstBetter) {
            ss[i] = s2; si[i] = i2; ss[ixj] = s1; si[ixj] = i1;
          }
        }
      }
      __syncthreads();
    }
  }
  for (int j = t; j < KEEP; j += 256) {
    int oldp = g * EG + si[j];
    int newp = g * KEEP + j;
    ei_new[newp]        = ei_old[oldp];
    ei_new[ENEW + newp] = ei_old[E_old + oldp];
    ew[newp] = fminf(fmaxf(ss[j], 0.f), 1.f);
  }
  __syncthreads();
  for (int q = t; q < KEEP * 32; q += 256) {
    int j = q >> 5, c4 = (q & 31) << 2;
    *(float4*)&e_new[(size_t)(g * KEEP + j) * 128 + c4] =
        *(const float4*)&e_old[(size_t)(g * EG + si[j]) * 128 + c4];
  }
}

// ---------- final MLP ----------
__global__ __launch_bounds__(128) void k_mlp(const float* __restrict__ xs,
                                             const float* __restrict__ Wc1, const float* __restrict__ bc1,
                                             const float* __restrict__ Wc2, const float* __restrict__ bc2,
                                             const float* __restrict__ Wc3, const float* __restrict__ bc3,
                                             float* __restrict__ out) {
  __shared__ float row[384];
  __shared__ float h1[128];
  __shared__ float h2[64];
  int g = blockIdx.x, t = threadIdx.x;
  for (int i = t; i < 384; i += 128) row[i] = xs[g * 384 + i];
  __syncthreads();
  float a = bc1[t];
  for (int k = 0; k < 384; ++k) a += row[k] * Wc1[k * 128 + t];
  h1[t] = fmaxf(a, 0.f);
  __syncthreads();
  if (t < 64) {
    float b = bc2[t];
    for (int k = 0; k < 128; ++k) b += h1[k] * Wc2[k * 64 + t];
    h2[t] = fmaxf(b, 0.f);
  }
  __syncthreads();
  float o = bc3[t];
  for (int k = 0; k < 64; ++k) o += h2[k] * Wc3[k * 128 + t];
  out[g * 128 + t] = o;
}

extern "C" void kernel_launch(void* const* d_in, const int* in_sizes, int n_in,
                              void* d_out, int out_size, void* d_ws, size_t ws_size,
                              hipStream_t stream) {
  (void)in_sizes; (void)n_in; (void)out_size; (void)ws_size;
  const int*   x_idx  = (const int*)d_in[0];
  const int*   b_idx  = (const int*)d_in[1];
  const int*   ei0    = (const int*)d_in[2];
  const float* atom_t = (const float*)d_in[4];
  const float* bond_t = (const float*)d_in[5];
  const float* W_gcn  = (const float*)d_in[6];
  const float* b_gcn  = (const float*)d_in[7];
  const float* root   = (const float*)d_in[8];
  const float* W_hyp  = (const float*)d_in[9];
  const float* b_hyp  = (const float*)d_in[10];
  const float* W_sc   = (const float*)d_in[11];
  const float* b_sc   = (const float*)d_in[12];
  const float* Wc1    = (const float*)d_in[13];
  const float* bc1_   = (const float*)d_in[14];
  const float* Wc2    = (const float*)d_in[15];
  const float* bc2_   = (const float*)d_in[16];
  const float* Wc3    = (const float*)d_in[17];
  const float* bc3_   = (const float*)d_in[18];
  float* out = (float*)d_out;

  // workspace layout
  float* x    = (float*)d_ws;
  float* h    = x    + (size_t)NTOT * D;
  float* eA   = h    + (size_t)NTOT * D;
  float* eB   = eA   + (size_t)E0 * D;
  float* score= eB   + (size_t)E0 * D;
  float* ew   = score+ E0;
  float* xs   = ew   + E0;
  int*   eiB  = (int*)(xs + BG * 384);
  int*   eiA2 = eiB + 2 * E0;

  hipMemsetAsync(xs, 0, BG * 384 * 4, stream);
  k_embed_x<<<NTOT * 32 / 256, 256, 0, stream>>>(x_idx, atom_t, x);
  k_embed_e<<<E0 * 32 / 256, 256, 0, stream>>>(b_idx, bond_t, eA);

  // ---- layer 0 ----
  k_gemm128<<<NTOT / 64, 256, 0, stream>>>(x, W_gcn, b_gcn, h);
  k_gcn_fused<EG0, false><<<BG, 1024, 0, stream>>>(ei0, E0, eA, h, nullptr, root, x, xs);
  k_gemm128<<<E0 / 64, 256, 0, stream>>>(eA, W_hyp, nullptr, eB);
  k_hyper_fused<EG0><<<BG, 1024, 0, stream>>>(ei0, E0, eB, b_hyp, W_sc, b_sc, eA, score);
  k_sortcompact<EG0, KP0, E1><<<BG, 256, 0, stream>>>(score, ei0, E0, eA, eiB, eB, ew);

  // ---- layer 1 ----
  k_gemm128<<<NTOT / 64, 256, 0, stream>>>(x, W_gcn + D * D, b_gcn + D, h);
  k_gcn_fused<KP0, true><<<BG, 1024, 0, stream>>>(eiB, E1, eB, h, ew, root + D, x, xs);
  k_gemm128<<<E1 / 64, 256, 0, stream>>>(eB, W_hyp + D * D, nullptr, eA);
  k_hyper_fused<KP0><<<BG, 1024, 0, stream>>>(eiB, E1, eA, b_hyp + D, W_sc + D, b_sc + 1, eB, score);
  k_sortcompact<KP0, KP1, E2><<<BG, 256, 0, stream>>>(score, eiB, E1, eB, eiA2, eA, ew);

  // ---- layer 2 ----
  k_gemm128<<<NTOT / 64, 256, 0, stream>>>(x, W_gcn + 2 * D * D, b_gcn + 2 * D, h);
  k_gcn_fused<KP1, true><<<BG, 1024, 0, stream>>>(eiA2, E2, eA, h, ew, root + 2 * D, x, xs);

  k_mlp<<<BG, 128, 0, stream>>>(xs, Wc1, bc1_, Wc2, bc2_, Wc3, bc3_, out);
}